// Round 1
// baseline (139.438 us; speedup 1.0000x reference)
//
#include <hip/hip_runtime.h>

#define T_SEQ 2048
#define C_DIM 128

typedef __attribute__((ext_vector_type(8))) short bf16x8;
typedef __attribute__((ext_vector_type(4))) float f32x4;

__device__ __forceinline__ unsigned short f2bf(float f) {
    union { float f; unsigned int u; } v; v.f = f;
    unsigned int r = v.u + 0x7FFFu + ((v.u >> 16) & 1u);
    return (unsigned short)(r >> 16);
}

// ---------------------------------------------------------------------------
// proj_kernel: computes one of q = (x@Wq^T)*C^-0.5, k = x@Wk^T, v^T = (x@Wv^T)^T
// grid (T/64, B, 3), block 256 (4 waves, each owns 16 output rows)
// ---------------------------------------------------------------------------
__global__ __launch_bounds__(256) void proj_kernel(
    const float* __restrict__ x,
    const float* __restrict__ Wq, const float* __restrict__ Wk,
    const float* __restrict__ Wv,
    unsigned short* __restrict__ qo, unsigned short* __restrict__ ko,
    unsigned short* __restrict__ vto)
{
    const int qt = blockIdx.x;     // 64-row tile index within T
    const int b  = blockIdx.y;
    const int z  = blockIdx.z;     // 0=q, 1=k, 2=v(transposed)
    const int tid  = threadIdx.x;
    const int lane = tid & 63;
    const int w    = tid >> 6;
    const int n16  = lane & 15;
    const int quad = lane >> 4;

    // W in bf16, row stride 136 (272 B -> 2-way bank aliasing only, free)
    __shared__ __align__(16) unsigned short Wl[128 * 136];   // 34816 B
    // x tile 64x136 (8704 elems) reused as vT 128x72 (9216 elems)
    __shared__ __align__(16) unsigned short Xl[9216];        // 18432 B

    const float* W = (z == 0) ? Wq : (z == 1) ? Wk : Wv;

    // ---- stage W -> LDS (fp32 -> bf16) ----
    #pragma unroll
    for (int i = 0; i < 16; ++i) {
        int e = (tid + i * 256) * 4;            // 16384 elements, 4 per step
        int r = e >> 7, c = e & 127;
        float4 v = *reinterpret_cast<const float4*>(W + r * 128 + c);
        unsigned short* p = &Wl[r * 136 + c];
        p[0] = f2bf(v.x); p[1] = f2bf(v.y); p[2] = f2bf(v.z); p[3] = f2bf(v.w);
    }
    // ---- stage x tile -> LDS (fp32 -> bf16) ----
    const float* xb = x + ((size_t)b * T_SEQ + (size_t)qt * 64) * C_DIM;
    #pragma unroll
    for (int i = 0; i < 8; ++i) {
        int e = (tid + i * 256) * 4;            // 8192 elements
        int r = e >> 7, c = e & 127;
        float4 v = *reinterpret_cast<const float4*>(xb + r * 128 + c);
        unsigned short* p = &Xl[r * 136 + c];
        p[0] = f2bf(v.x); p[1] = f2bf(v.y); p[2] = f2bf(v.z); p[3] = f2bf(v.w);
    }
    __syncthreads();

    // ---- A fragments: wave w owns rows w*16 .. w*16+15 ----
    const int arow = w * 16 + n16;
    bf16x8 afr[4];
    #pragma unroll
    for (int kk = 0; kk < 4; ++kk)
        afr[kk] = *reinterpret_cast<const bf16x8*>(&Xl[arow * 136 + kk * 32 + quad * 8]);

    f32x4 acc[8];
    #pragma unroll
    for (int nt = 0; nt < 8; ++nt) acc[nt] = (f32x4){0.f, 0.f, 0.f, 0.f};

    #pragma unroll
    for (int kk = 0; kk < 4; ++kk) {
        #pragma unroll
        for (int nt = 0; nt < 8; ++nt) {
            bf16x8 bfr = *reinterpret_cast<const bf16x8*>(
                &Wl[(nt * 16 + n16) * 136 + kk * 32 + quad * 8]);
            acc[nt] = __builtin_amdgcn_mfma_f32_16x16x32_bf16(afr[kk], bfr, acc[nt], 0, 0, 0);
        }
    }

    const int trow_base = w * 16 + quad * 4;    // local t-row of acc reg r
    if (z < 2) {
        const float scale = (z == 0) ? 0.08838834764831845f : 1.0f;  // C^-0.5 folded into q
        unsigned short* dst = (z == 0 ? qo : ko) +
            ((size_t)b * T_SEQ + (size_t)qt * 64) * C_DIM;
        #pragma unroll
        for (int nt = 0; nt < 8; ++nt)
            #pragma unroll
            for (int r = 0; r < 4; ++r)
                dst[(size_t)(trow_base + r) * C_DIM + nt * 16 + n16] =
                    f2bf(acc[nt][r] * scale);
    } else {
        // transpose v tile via LDS: vT[d][t_local], row stride 72
        __syncthreads();                         // everyone done reading Xl as x
        #pragma unroll
        for (int nt = 0; nt < 8; ++nt)
            #pragma unroll
            for (int r = 0; r < 4; ++r)
                Xl[(nt * 16 + n16) * 72 + trow_base + r] = f2bf(acc[nt][r]);
        __syncthreads();
        // write vT tile: 128 rows x 64 cols, coalesced 16B chunks
        unsigned short* dst = vto + (size_t)b * C_DIM * T_SEQ + (size_t)qt * 64;
        #pragma unroll
        for (int i = 0; i < 4; ++i) {
            int e = tid + i * 256;               // 1024 chunks of 8 bf16
            int d = e >> 3, cv = (e & 7) * 8;
            *reinterpret_cast<uint4*>(dst + (size_t)d * T_SEQ + cv) =
                *reinterpret_cast<const uint4*>(&Xl[d * 72 + cv]);
        }
    }
}

// ---------------------------------------------------------------------------
// attn_kernel: flash attention, causal. grid (T/64, B), block 256.
// Each wave owns 16 query rows; K-tile = 64 keys per iteration.
// q is pre-scaled by C^-0.5. v is stored transposed [c][t].
// ---------------------------------------------------------------------------
__global__ __launch_bounds__(256) void attn_kernel(
    const unsigned short* __restrict__ qb,
    const unsigned short* __restrict__ kb,
    const unsigned short* __restrict__ vtb,
    float* __restrict__ out)
{
    const int qt = blockIdx.x;
    const int b  = blockIdx.y;
    const int tid  = threadIdx.x;
    const int lane = tid & 63;
    const int w    = tid >> 6;
    const int n16  = lane & 15;
    const int quad = lane >> 4;

    __shared__ __align__(16) unsigned short Kl[64 * 136];    // K tile [s][c]
    __shared__ __align__(16) unsigned short Vl[128 * 72];    // V^T tile [c][s]
    __shared__ __align__(16) unsigned short Pl[4][16 * 72];  // per-wave P [q][s]

    const size_t bT = (size_t)b * T_SEQ;
    const int qbase = qt * 64 + w * 16;

    // Q fragments straight from global (one-time, 16 KB/block)
    bf16x8 qfr[4];
    #pragma unroll
    for (int kk = 0; kk < 4; ++kk)
        qfr[kk] = *reinterpret_cast<const bf16x8*>(
            qb + (bT + qbase + n16) * C_DIM + kk * 32 + quad * 8);

    f32x4 o[8];
    #pragma unroll
    for (int ct = 0; ct < 8; ++ct) o[ct] = (f32x4){0.f, 0.f, 0.f, 0.f};
    float m[4], l[4];
    #pragma unroll
    for (int r = 0; r < 4; ++r) { m[r] = -INFINITY; l[r] = 0.f; }

    for (int kt = 0; kt <= qt; ++kt) {
        __syncthreads();   // previous iteration's PV reads done before restage
        // ---- stage K tile [64][128] -> Kl ----
        const unsigned short* ks = kb + (bT + (size_t)kt * 64) * C_DIM;
        #pragma unroll
        for (int i = 0; i < 4; ++i) {
            int e = tid + i * 256;               // 1024 chunks of 8
            int r = e >> 4, c = (e & 15) * 8;
            *reinterpret_cast<uint4*>(&Kl[r * 136 + c]) =
                *reinterpret_cast<const uint4*>(ks + r * 128 + c);
        }
        // ---- stage V^T tile [128][64] -> Vl ----
        const unsigned short* vs = vtb + (size_t)b * C_DIM * T_SEQ + (size_t)kt * 64;
        #pragma unroll
        for (int i = 0; i < 4; ++i) {
            int e = tid + i * 256;
            int d = e >> 3, c = (e & 7) * 8;
            *reinterpret_cast<uint4*>(&Vl[d * 72 + c]) =
                *reinterpret_cast<const uint4*>(vs + (size_t)d * T_SEQ + c);
        }
        __syncthreads();

        // ---- S = Q K^T (16 queries x 64 keys per wave) ----
        f32x4 s[4];
        #pragma unroll
        for (int nt = 0; nt < 4; ++nt) s[nt] = (f32x4){0.f, 0.f, 0.f, 0.f};
        #pragma unroll
        for (int kk = 0; kk < 4; ++kk)
            #pragma unroll
            for (int nt = 0; nt < 4; ++nt) {
                bf16x8 bfr = *reinterpret_cast<const bf16x8*>(
                    &Kl[(nt * 16 + n16) * 136 + kk * 32 + quad * 8]);
                s[nt] = __builtin_amdgcn_mfma_f32_16x16x32_bf16(qfr[kk], bfr, s[nt], 0, 0, 0);
            }

        // ---- causal mask on diagonal tile ----
        if (kt == qt) {
            #pragma unroll
            for (int nt = 0; nt < 4; ++nt)
                #pragma unroll
                for (int r = 0; r < 4; ++r) {
                    int sabs = kt * 64 + nt * 16 + n16;
                    int qabs = qbase + quad * 4 + r;
                    if (sabs > qabs) s[nt][r] = -1e30f;
                }
        }

        // ---- online softmax (rows live in (quad,reg); cols in lanes 0..15) ----
        float alpha[4];
        #pragma unroll
        for (int r = 0; r < 4; ++r) {
            float tmax = fmaxf(fmaxf(s[0][r], s[1][r]), fmaxf(s[2][r], s[3][r]));
            #pragma unroll
            for (int off = 1; off < 16; off <<= 1)
                tmax = fmaxf(tmax, __shfl_xor(tmax, off));
            float mn = fmaxf(m[r], tmax);
            alpha[r] = __expf(m[r] - mn);        // exp(-inf)=0 on first tile
            float tsum = 0.f;
            #pragma unroll
            for (int nt = 0; nt < 4; ++nt) {
                float p = __expf(s[nt][r] - mn);
                s[nt][r] = p;
                tsum += p;
            }
            #pragma unroll
            for (int off = 1; off < 16; off <<= 1)
                tsum += __shfl_xor(tsum, off);
            l[r] = l[r] * alpha[r] + tsum;
            m[r] = mn;
        }
        #pragma unroll
        for (int ct = 0; ct < 8; ++ct)
            #pragma unroll
            for (int r = 0; r < 4; ++r)
                o[ct][r] *= alpha[r];

        // ---- P: C-layout -> LDS -> A-layout (per-wave region, no barrier) ----
        unsigned short* pw = Pl[w];
        #pragma unroll
        for (int nt = 0; nt < 4; ++nt)
            #pragma unroll
            for (int r = 0; r < 4; ++r)
                pw[(quad * 4 + r) * 72 + nt * 16 + n16] = f2bf(s[nt][r]);

        // ---- O += P V ----
        #pragma unroll
        for (int kk2 = 0; kk2 < 2; ++kk2) {
            bf16x8 afr = *reinterpret_cast<const bf16x8*>(
                &pw[n16 * 72 + kk2 * 32 + quad * 8]);
            #pragma unroll
            for (int ct = 0; ct < 8; ++ct) {
                bf16x8 bfr = *reinterpret_cast<const bf16x8*>(
                    &Vl[(ct * 16 + n16) * 72 + kk2 * 32 + quad * 8]);
                o[ct] = __builtin_amdgcn_mfma_f32_16x16x32_bf16(afr, bfr, o[ct], 0, 0, 0);
            }
        }
    }

    // ---- epilogue: out = O / l ----
    float* outp = out + (bT + qbase) * C_DIM;
    #pragma unroll
    for (int r = 0; r < 4; ++r) {
        float inv = 1.0f / l[r];
        #pragma unroll
        for (int ct = 0; ct < 8; ++ct)
            outp[(size_t)(quad * 4 + r) * C_DIM + ct * 16 + n16] = o[ct][r] * inv;
    }
}

extern "C" void kernel_launch(void* const* d_in, const int* in_sizes, int n_in,
                              void* d_out, int out_size, void* d_ws, size_t ws_size,
                              hipStream_t stream) {
    const int B = 8;
    const float* x  = (const float*)d_in[0];
    const float* Wk = (const float*)d_in[1];   // setup_inputs order: x, Wk, Wq, Wv
    const float* Wq = (const float*)d_in[2];
    const float* Wv = (const float*)d_in[3];

    unsigned short* qw = (unsigned short*)d_ws;            // [B][T][C] bf16, 4 MB
    unsigned short* kw = qw + (size_t)B * T_SEQ * C_DIM;   // [B][T][C] bf16, 4 MB
    unsigned short* vw = kw + (size_t)B * T_SEQ * C_DIM;   // [B][C][T] bf16, 4 MB

    dim3 g1(T_SEQ / 64, B, 3);
    proj_kernel<<<g1, 256, 0, stream>>>(x, Wq, Wk, Wv, qw, kw, vw);

    dim3 g2(T_SEQ / 64, B);
    attn_kernel<<<g2, 256, 0, stream>>>(qw, kw, vw, (float*)d_out);
}

// Round 2
// 135.667 us; speedup vs baseline: 1.0278x; 1.0278x over previous
//
#include <hip/hip_runtime.h>

#define T_SEQ 2048
#define C_DIM 128
#define S_QK 0.08838834764831845f

typedef __attribute__((ext_vector_type(8))) short bf16x8;
typedef __attribute__((ext_vector_type(4))) float f32x4;

// ---- workspace layout (bytes) ----
// qw  bf16 [8][2048][128]            @ 0         (4,194,304)
// kw  bf16 [8][2048][128]            @ 4194304   (4,194,304)
// vw  bf16 [8][128][2048] (V^T)      @ 8388608   (4,194,304)
// Opart f32 [8*72][64][128]          @ 12582912  (18,874,368)
// ml  float2 [8*72][64]              @ 31457280  (294,912)
// xbf bf16 [8*2048][128]             @ 31752192  (4,194,304)
// wbf bf16 [3][128][128]             @ 35946496  (98,304)
#define OPART_OFF 12582912UL
#define ML_OFF    31457280UL
#define XBF_OFF   31752192UL
#define WBF_OFF   35946496UL

__device__ __forceinline__ unsigned short f2bf(float f) {
    union { float f; unsigned int u; } v; v.f = f;
    unsigned int r = v.u + 0x7FFFu + ((v.u >> 16) & 1u);
    return (unsigned short)(r >> 16);
}

// compact chunk-slot base within a batch, for qt>=8 (chunks of 8 key-tiles)
__device__ __forceinline__ int chunk_base(int qt) {
    int g = qt >> 3;                       // 1,2,3
    if (g == 1) return (qt - 8) * 2;
    if (g == 2) return 16 + (qt - 16) * 3;
    return 40 + (qt - 24) * 4;             // total 72 per batch
}

// ---------------------------------------------------------------------------
// prep: fp32 -> bf16 for x and W (scale folded into Wq). One float4 per thread.
// x: 524288 float4 chunks, W: 3*4096 chunks. grid 2096 x 256.
// ---------------------------------------------------------------------------
__global__ __launch_bounds__(256) void prep_kernel(
    const float* __restrict__ x,
    const float* __restrict__ Wk, const float* __restrict__ Wq,
    const float* __restrict__ Wv,
    unsigned short* __restrict__ xbf, unsigned short* __restrict__ wbf)
{
    int idx = blockIdx.x * 256 + threadIdx.x;
    const float* src;
    unsigned short* dst;
    float scale = 1.0f;
    if (idx < 524288) {
        src = x + (size_t)idx * 4;
        dst = xbf + (size_t)idx * 4;
    } else {
        int wi  = idx - 524288;
        int sel = wi >> 12;                 // 0=q,1=k,2=v
        int off = (wi & 4095) * 4;
        src = (sel == 0 ? Wq : sel == 1 ? Wk : Wv) + off;
        dst = wbf + sel * 16384 + off;
        if (sel == 0) scale = S_QK;
    }
    float4 v = *reinterpret_cast<const float4*>(src);
    ushort4 o;
    o.x = f2bf(v.x * scale); o.y = f2bf(v.y * scale);
    o.z = f2bf(v.z * scale); o.w = f2bf(v.w * scale);
    *reinterpret_cast<ushort4*>(dst) = o;
}

// ---------------------------------------------------------------------------
// proj: one of q|k|vT = xbf @ W^T. grid (256 row-tiles, 3), block 256.
// ---------------------------------------------------------------------------
__global__ __launch_bounds__(256) void proj_kernel(
    const unsigned short* __restrict__ xbf,
    const unsigned short* __restrict__ wbf,
    unsigned short* __restrict__ qo, unsigned short* __restrict__ ko,
    unsigned short* __restrict__ vto)
{
    const int rt = blockIdx.x;             // 64-row tile over B*T
    const int z  = blockIdx.y;             // 0=q, 1=k, 2=v(transposed)
    const int tid  = threadIdx.x;
    const int lane = tid & 63;
    const int w    = tid >> 6;
    const int n16  = lane & 15;
    const int quad = lane >> 4;

    __shared__ __align__(16) unsigned short Wl[128 * 136];   // 34816 B
    __shared__ __align__(16) unsigned short Xl[9216];        // 18432 B (x tile / out stage)

    const unsigned short* Wsrc = wbf + z * 16384;
    #pragma unroll
    for (int i = 0; i < 8; ++i) {
        int e = (tid + i * 256) * 8;       // 16384 elements, 8 per op
        int r = e >> 7, c = e & 127;
        *reinterpret_cast<uint4*>(&Wl[r * 136 + c]) =
            *reinterpret_cast<const uint4*>(Wsrc + e);
    }
    const unsigned short* xrow = xbf + (size_t)rt * 64 * C_DIM;
    #pragma unroll
    for (int i = 0; i < 4; ++i) {
        int e = (tid + i * 256) * 8;       // 8192 elements
        int r = e >> 7, c = e & 127;
        *reinterpret_cast<uint4*>(&Xl[r * 136 + c]) =
            *reinterpret_cast<const uint4*>(xrow + e);
    }
    __syncthreads();

    const int arow = w * 16 + n16;
    bf16x8 afr[4];
    #pragma unroll
    for (int kk = 0; kk < 4; ++kk)
        afr[kk] = *reinterpret_cast<const bf16x8*>(&Xl[arow * 136 + kk * 32 + quad * 8]);

    f32x4 acc[8];
    #pragma unroll
    for (int nt = 0; nt < 8; ++nt) acc[nt] = (f32x4){0.f, 0.f, 0.f, 0.f};
    #pragma unroll
    for (int kk = 0; kk < 4; ++kk)
        #pragma unroll
        for (int nt = 0; nt < 8; ++nt) {
            bf16x8 bfr = *reinterpret_cast<const bf16x8*>(
                &Wl[(nt * 16 + n16) * 136 + kk * 32 + quad * 8]);
            acc[nt] = __builtin_amdgcn_mfma_f32_16x16x32_bf16(afr[kk], bfr, acc[nt], 0, 0, 0);
        }

    const int trow_base = w * 16 + quad * 4;
    __syncthreads();                       // all waves done reading Xl
    if (z < 2) {
        // stage [64][136] then coalesced uint4 stores
        #pragma unroll
        for (int nt = 0; nt < 8; ++nt)
            #pragma unroll
            for (int r = 0; r < 4; ++r)
                Xl[(trow_base + r) * 136 + nt * 16 + n16] = f2bf(acc[nt][r]);
        __syncthreads();
        unsigned short* dst = (z == 0 ? qo : ko) + (size_t)rt * 64 * C_DIM;
        #pragma unroll
        for (int i = 0; i < 4; ++i) {
            int e = (tid + i * 256) * 8;
            int r = e >> 7, c = e & 127;
            *reinterpret_cast<uint4*>(dst + e) =
                *reinterpret_cast<const uint4*>(&Xl[r * 136 + c]);
        }
    } else {
        // transpose v tile: vT[d][t_local], row stride 72
        const int b  = rt >> 5;
        const int qt = rt & 31;
        #pragma unroll
        for (int nt = 0; nt < 8; ++nt)
            #pragma unroll
            for (int r = 0; r < 4; ++r)
                Xl[(nt * 16 + n16) * 72 + trow_base + r] = f2bf(acc[nt][r]);
        __syncthreads();
        unsigned short* dst = vto + (size_t)b * C_DIM * T_SEQ + (size_t)qt * 64;
        #pragma unroll
        for (int i = 0; i < 4; ++i) {
            int e = tid + i * 256;
            int d = e >> 3, cv = (e & 7) * 8;
            *reinterpret_cast<uint4*>(dst + (size_t)d * T_SEQ + cv) =
                *reinterpret_cast<const uint4*>(&Xl[d * 72 + cv]);
        }
    }
}

// ---------------------------------------------------------------------------
// attn pass 1: split-K flash attention. grid (32 qtiles, 4 chunks, 8 batch).
// chunk covers key-tiles [chunk*8, min(chunk*8+8, qt+1)). Inactive if
// chunk*8 > qt. qt<8 (single chunk) writes final output; else partial O,m,l.
// ---------------------------------------------------------------------------
__global__ __launch_bounds__(256) void attn_kernel(
    const unsigned short* __restrict__ qb,
    const unsigned short* __restrict__ kb,
    const unsigned short* __restrict__ vtb,
    float* __restrict__ opart, float2* __restrict__ mlbuf,
    float* __restrict__ out)
{
    const int qt    = blockIdx.x;
    const int chunk = blockIdx.y;
    const int b     = blockIdx.z;
    if (chunk * 8 > qt) return;

    const int tid  = threadIdx.x;
    const int lane = tid & 63;
    const int w    = tid >> 6;
    const int n16  = lane & 15;
    const int quad = lane >> 4;

    __shared__ __align__(16) unsigned short Kl[64 * 136];    // 17408 B
    __shared__ __align__(16) unsigned short Vl[128 * 72];    // 18432 B
    __shared__ __align__(16) unsigned short Pl[4][16 * 72];  //  9216 B

    const size_t bT = (size_t)b * T_SEQ;
    const int qbase = qt * 64 + w * 16;

    bf16x8 qfr[4];
    #pragma unroll
    for (int kk = 0; kk < 4; ++kk)
        qfr[kk] = *reinterpret_cast<const bf16x8*>(
            qb + (bT + qbase + n16) * C_DIM + kk * 32 + quad * 8);

    f32x4 o[8];
    #pragma unroll
    for (int ct = 0; ct < 8; ++ct) o[ct] = (f32x4){0.f, 0.f, 0.f, 0.f};
    float m[4], l[4];
    #pragma unroll
    for (int r = 0; r < 4; ++r) { m[r] = -INFINITY; l[r] = 0.f; }

    const int k0 = chunk * 8;
    const int k1 = min(k0 + 8, qt + 1);

    for (int kt = k0; kt < k1; ++kt) {
        __syncthreads();
        const unsigned short* ks = kb + (bT + (size_t)kt * 64) * C_DIM;
        #pragma unroll
        for (int i = 0; i < 4; ++i) {
            int e = tid + i * 256;
            int r = e >> 4, c = (e & 15) * 8;
            *reinterpret_cast<uint4*>(&Kl[r * 136 + c]) =
                *reinterpret_cast<const uint4*>(ks + r * 128 + c);
        }
        const unsigned short* vs = vtb + (size_t)b * C_DIM * T_SEQ + (size_t)kt * 64;
        #pragma unroll
        for (int i = 0; i < 4; ++i) {
            int e = tid + i * 256;
            int d = e >> 3, c = (e & 7) * 8;
            *reinterpret_cast<uint4*>(&Vl[d * 72 + c]) =
                *reinterpret_cast<const uint4*>(vs + (size_t)d * T_SEQ + c);
        }
        __syncthreads();

        f32x4 s[4];
        #pragma unroll
        for (int nt = 0; nt < 4; ++nt) s[nt] = (f32x4){0.f, 0.f, 0.f, 0.f};
        #pragma unroll
        for (int kk = 0; kk < 4; ++kk)
            #pragma unroll
            for (int nt = 0; nt < 4; ++nt) {
                bf16x8 bfr = *reinterpret_cast<const bf16x8*>(
                    &Kl[(nt * 16 + n16) * 136 + kk * 32 + quad * 8]);
                s[nt] = __builtin_amdgcn_mfma_f32_16x16x32_bf16(qfr[kk], bfr, s[nt], 0, 0, 0);
            }

        if (kt == qt) {
            #pragma unroll
            for (int nt = 0; nt < 4; ++nt)
                #pragma unroll
                for (int r = 0; r < 4; ++r) {
                    int sabs = kt * 64 + nt * 16 + n16;
                    int qabs = qbase + quad * 4 + r;
                    if (sabs > qabs) s[nt][r] = -1e30f;
                }
        }

        float alpha[4];
        #pragma unroll
        for (int r = 0; r < 4; ++r) {
            float tmax = fmaxf(fmaxf(s[0][r], s[1][r]), fmaxf(s[2][r], s[3][r]));
            #pragma unroll
            for (int off = 1; off < 16; off <<= 1)
                tmax = fmaxf(tmax, __shfl_xor(tmax, off));
            float mn = fmaxf(m[r], tmax);
            alpha[r] = __expf(m[r] - mn);
            float tsum = 0.f;
            #pragma unroll
            for (int nt = 0; nt < 4; ++nt) {
                float p = __expf(s[nt][r] - mn);
                s[nt][r] = p;
                tsum += p;
            }
            #pragma unroll
            for (int off = 1; off < 16; off <<= 1)
                tsum += __shfl_xor(tsum, off);
            l[r] = l[r] * alpha[r] + tsum;
            m[r] = mn;
        }
        #pragma unroll
        for (int ct = 0; ct < 8; ++ct)
            #pragma unroll
            for (int r = 0; r < 4; ++r)
                o[ct][r] *= alpha[r];

        unsigned short* pw = Pl[w];
        #pragma unroll
        for (int nt = 0; nt < 4; ++nt)
            #pragma unroll
            for (int r = 0; r < 4; ++r)
                pw[(quad * 4 + r) * 72 + nt * 16 + n16] = f2bf(s[nt][r]);

        #pragma unroll
        for (int kk2 = 0; kk2 < 2; ++kk2) {
            bf16x8 afr = *reinterpret_cast<const bf16x8*>(
                &pw[n16 * 72 + kk2 * 32 + quad * 8]);
            #pragma unroll
            for (int ct = 0; ct < 8; ++ct) {
                bf16x8 bfr = *reinterpret_cast<const bf16x8*>(
                    &Vl[(ct * 16 + n16) * 72 + kk2 * 32 + quad * 8]);
                o[ct] = __builtin_amdgcn_mfma_f32_16x16x32_bf16(afr, bfr, o[ct], 0, 0, 0);
            }
        }
    }

    if (qt < 8) {
        // single chunk: final output
        float* outp = out + (bT + qbase) * C_DIM;
        #pragma unroll
        for (int r = 0; r < 4; ++r) {
            float inv = 1.0f / l[r];
            #pragma unroll
            for (int ct = 0; ct < 8; ++ct)
                outp[(size_t)(quad * 4 + r) * C_DIM + ct * 16 + n16] = o[ct][r] * inv;
        }
    } else {
        const int slot = b * 72 + chunk_base(qt) + chunk;
        float* op = opart + (size_t)slot * 8192;
        #pragma unroll
        for (int r = 0; r < 4; ++r) {
            int row = w * 16 + quad * 4 + r;
            #pragma unroll
            for (int ct = 0; ct < 8; ++ct)
                op[row * 128 + ct * 16 + n16] = o[ct][r];
            if (n16 == 0)
                mlbuf[(size_t)slot * 64 + row] = make_float2(m[r], l[r]);
        }
    }
}

// ---------------------------------------------------------------------------
// merge: combine <=4 partials per (b, qt>=8). grid (24, 8), block 256.
// ---------------------------------------------------------------------------
__global__ __launch_bounds__(256) void merge_kernel(
    const float* __restrict__ opart, const float2* __restrict__ mlbuf,
    float* __restrict__ out)
{
    const int qt = 8 + blockIdx.x;
    const int b  = blockIdx.y;
    const int nch  = (qt >> 3) + 1;
    const int base = b * 72 + chunk_base(qt);
    const int row = threadIdx.x >> 2;
    const int c0  = (threadIdx.x & 3) * 32;

    float mi[4], li[4], wgt[4];
    float M = -INFINITY;
    for (int i = 0; i < nch; ++i) {
        float2 t = mlbuf[(size_t)(base + i) * 64 + row];
        mi[i] = t.x; li[i] = t.y;
        M = fmaxf(M, t.x);
    }
    float L = 0.f;
    for (int i = 0; i < nch; ++i) {
        wgt[i] = __expf(mi[i] - M);
        L += li[i] * wgt[i];
    }
    const float inv = 1.0f / L;

    float* orow = out + ((size_t)(b * T_SEQ + qt * 64 + row)) * C_DIM;
    #pragma unroll
    for (int j = 0; j < 8; ++j) {
        int col = c0 + j * 4;
        float ax = 0.f, ay = 0.f, az = 0.f, aw = 0.f;
        for (int i = 0; i < nch; ++i) {
            float4 p = *reinterpret_cast<const float4*>(
                opart + (size_t)(base + i) * 8192 + row * 128 + col);
            ax += wgt[i] * p.x; ay += wgt[i] * p.y;
            az += wgt[i] * p.z; aw += wgt[i] * p.w;
        }
        float4 r4; r4.x = ax * inv; r4.y = ay * inv; r4.z = az * inv; r4.w = aw * inv;
        *reinterpret_cast<float4*>(orow + col) = r4;
    }
}

extern "C" void kernel_launch(void* const* d_in, const int* in_sizes, int n_in,
                              void* d_out, int out_size, void* d_ws, size_t ws_size,
                              hipStream_t stream) {
    const float* x  = (const float*)d_in[0];
    const float* Wk = (const float*)d_in[1];
    const float* Wq = (const float*)d_in[2];
    const float* Wv = (const float*)d_in[3];

    unsigned short* qw  = (unsigned short*)d_ws;
    unsigned short* kw  = qw + 2097152;
    unsigned short* vw  = kw + 2097152;
    float*          opart = (float*)((char*)d_ws + OPART_OFF);
    float2*         mlb   = (float2*)((char*)d_ws + ML_OFF);
    unsigned short* xbf   = (unsigned short*)((char*)d_ws + XBF_OFF);
    unsigned short* wbf   = (unsigned short*)((char*)d_ws + WBF_OFF);

    prep_kernel<<<2096, 256, 0, stream>>>(x, Wk, Wq, Wv, xbf, wbf);
    proj_kernel<<<dim3(256, 3), 256, 0, stream>>>(xbf, wbf, qw, kw, vw);
    attn_kernel<<<dim3(32, 4, 8), 256, 0, stream>>>(qw, kw, vw, opart, mlb, (float*)d_out);
    merge_kernel<<<dim3(24, 8), 256, 0, stream>>>(opart, mlb, (float*)d_out);
}